// Round 1
// baseline (2382.551 us; speedup 1.0000x reference)
//
#include <hip/hip_runtime.h>

#define NN   50000
#define NE   600000
#define HID  128
#define NOUT_ 64
#define NG   256

static __global__ void k_init_deg(float* __restrict__ deg) {
  int i = blockIdx.x * 256 + threadIdx.x;
  if (i < NN) deg[i] = 1.0f;  // self-loop
}

static __global__ void k_count_deg(const int* __restrict__ row, float* __restrict__ deg) {
  int e = blockIdx.x * 256 + threadIdx.x;
  if (e < NE) atomicAdd(&deg[row[e]], 1.0f);
}

static __global__ void k_dinv(float* __restrict__ deg) {
  int i = blockIdx.x * 256 + threadIdx.x;
  if (i < NN) deg[i] = rsqrtf(deg[i]);  // deg >= 1 always (self-loop)
}

static __global__ void k_gather(const int* __restrict__ H, const float* __restrict__ emb,
                                float* __restrict__ x) {
  int t = blockIdx.x * 256 + threadIdx.x;
  int i = t >> 5;
  if (i >= NN) return;
  int j = (t & 31) << 2;
  *reinterpret_cast<float4*>(&x[i * HID + j]) =
      *reinterpret_cast<const float4*>(&emb[H[i] * HID + j]);
}

// h = x @ W^T + b   (x: NN x 128, W: 128 x 128 row-major, h: NN x 128)
static __global__ __launch_bounds__(256) void k_gemm(
    const float* __restrict__ x, const float* __restrict__ W,
    const float* __restrict__ b, float* __restrict__ h) {
  __shared__ float xsT[64][68];  // [k][row], pad 68: aligned float4 reads, conflict-free
  __shared__ float wsT[64][68];  // [k][col]
  const int row0 = blockIdx.x * 64;
  const int col0 = blockIdx.y * 64;
  const int tid = threadIdx.x;
  const int tx = tid & 15, ty = tid >> 4;
  const int c0 = tx * 4, r0 = ty * 4;
  float acc[4][4] = {};
  for (int half = 0; half < 2; ++half) {
    const int kbase = half * 64;
    for (int it = 0; it < 4; ++it) {
      int idx = tid + it * 256;       // 0..1023 float4 ids
      int r = idx >> 4;               // 0..63 (x-row / W-col)
      int k4 = (idx & 15) << 2;       // 0..60
      int gr = row0 + r;
      float4 xv = (gr < NN)
          ? *reinterpret_cast<const float4*>(&x[gr * HID + kbase + k4])
          : make_float4(0.f, 0.f, 0.f, 0.f);
      xsT[k4 + 0][r] = xv.x; xsT[k4 + 1][r] = xv.y;
      xsT[k4 + 2][r] = xv.z; xsT[k4 + 3][r] = xv.w;
      float4 wv = *reinterpret_cast<const float4*>(&W[(col0 + r) * HID + kbase + k4]);
      wsT[k4 + 0][r] = wv.x; wsT[k4 + 1][r] = wv.y;
      wsT[k4 + 2][r] = wv.z; wsT[k4 + 3][r] = wv.w;
    }
    __syncthreads();
#pragma unroll 8
    for (int k = 0; k < 64; ++k) {
      float xv[4], wv[4];
      *reinterpret_cast<float4*>(xv) = *reinterpret_cast<const float4*>(&xsT[k][r0]);
      *reinterpret_cast<float4*>(wv) = *reinterpret_cast<const float4*>(&wsT[k][c0]);
#pragma unroll
      for (int r = 0; r < 4; ++r)
#pragma unroll
        for (int c = 0; c < 4; ++c)
          acc[r][c] += xv[r] * wv[c];
    }
    __syncthreads();
  }
#pragma unroll
  for (int r = 0; r < 4; ++r) {
    int gr = row0 + r0 + r;
    if (gr < NN) {
      float4 o;
      o.x = acc[r][0] + b[col0 + c0 + 0];
      o.y = acc[r][1] + b[col0 + c0 + 1];
      o.z = acc[r][2] + b[col0 + c0 + 2];
      o.w = acc[r][3] + b[col0 + c0 + 3];
      *reinterpret_cast<float4*>(&h[gr * HID + col0 + c0]) = o;
    }
  }
}

// g = h * dinv (in place), agg initialized to g (self-loop contribution)
static __global__ void k_scale(float* __restrict__ h, float* __restrict__ agg,
                               const float* __restrict__ dinv) {
  int t = blockIdx.x * 256 + threadIdx.x;
  int i = t >> 5;
  if (i >= NN) return;
  int j = (t & 31) << 2;
  float d = dinv[i];
  float4 v = *reinterpret_cast<const float4*>(&h[i * HID + j]);
  v.x *= d; v.y *= d; v.z *= d; v.w *= d;
  *reinterpret_cast<float4*>(&h[i * HID + j]) = v;
  *reinterpret_cast<float4*>(&agg[i * HID + j]) = v;
}

// agg[row] += g[col] per edge (32 lanes/edge, float4 each)
static __global__ void k_edges(const int* __restrict__ row, const int* __restrict__ col,
                               const float* __restrict__ g, float* __restrict__ agg) {
  int t = blockIdx.x * 256 + threadIdx.x;
  int e = t >> 5;
  if (e >= NE) return;
  int j = (t & 31) << 2;
  int r = row[e], c = col[e];
  float4 v = *reinterpret_cast<const float4*>(&g[c * HID + j]);
  float* dst = &agg[r * HID + j];
  atomicAdd(dst + 0, v.x);
  atomicAdd(dst + 1, v.y);
  atomicAdd(dst + 2, v.z);
  atomicAdd(dst + 3, v.w);
}

// x = relu(agg * dinv)
static __global__ void k_relu_scale(const float* __restrict__ agg,
                                    const float* __restrict__ dinv,
                                    float* __restrict__ x) {
  int t = blockIdx.x * 256 + threadIdx.x;
  int i = t >> 5;
  if (i >= NN) return;
  int j = (t & 31) << 2;
  float d = dinv[i];
  float4 v = *reinterpret_cast<const float4*>(&agg[i * HID + j]);
  v.x = fmaxf(v.x * d, 0.f);
  v.y = fmaxf(v.y * d, 0.f);
  v.z = fmaxf(v.z * d, 0.f);
  v.w = fmaxf(v.w * d, 0.f);
  *reinterpret_cast<float4*>(&x[i * HID + j]) = v;
}

static __global__ void k_pool(const int* __restrict__ batch, const float* __restrict__ x,
                              float* __restrict__ pooled, float* __restrict__ cnt) {
  int t = blockIdx.x * 256 + threadIdx.x;
  int i = t >> 5;
  if (i >= NN) return;
  int j = (t & 31) << 2;
  int g = batch[i];
  float4 v = *reinterpret_cast<const float4*>(&x[i * HID + j]);
  float* dst = &pooled[g * HID + j];
  atomicAdd(dst + 0, v.x);
  atomicAdd(dst + 1, v.y);
  atomicAdd(dst + 2, v.z);
  atomicAdd(dst + 3, v.w);
  if (j == 0) atomicAdd(&cnt[g], 1.0f);
}

static __global__ void k_out(const float* __restrict__ pooled, const float* __restrict__ cnt,
                             const float* __restrict__ Wout, const float* __restrict__ bout,
                             float* __restrict__ out) {
  int g = blockIdx.x;
  int o = threadIdx.x;
  float inv = 1.0f / fmaxf(cnt[g], 1.0f);
  float acc = 0.f;
  for (int k = 0; k < HID; k += 4) {
    float4 p = *reinterpret_cast<const float4*>(&pooled[g * HID + k]);
    float4 w = *reinterpret_cast<const float4*>(&Wout[o * HID + k]);
    acc += p.x * w.x + p.y * w.y + p.z * w.z + p.w * w.w;
  }
  out[g * NOUT_ + o] = acc * inv + bout[o];
}

extern "C" void kernel_launch(void* const* d_in, const int* in_sizes, int n_in,
                              void* d_out, int out_size, void* d_ws, size_t ws_size,
                              hipStream_t stream) {
  const int* H     = (const int*)d_in[0];
  const int* ei    = (const int*)d_in[1];
  const int* row   = ei;
  const int* col   = ei + NE;
  const int* batch = (const int*)d_in[2];
  const float* emb  = (const float*)d_in[3];
  const float* W1   = (const float*)d_in[4];
  const float* b1   = (const float*)d_in[5];
  const float* W2   = (const float*)d_in[6];
  const float* b2   = (const float*)d_in[7];
  const float* Wout = (const float*)d_in[8];
  const float* bout = (const float*)d_in[9];

  char* ws = (char*)d_ws;
  size_t off = 0;
  auto alloc = [&](size_t bytes) -> float* {
    float* p = (float*)(ws + off);
    off += (bytes + 255) & ~(size_t)255;
    return p;
  };
  float* deg    = alloc((size_t)NN * 4);            // becomes dinv
  float* xbuf   = alloc((size_t)NN * HID * 4);
  float* hbuf   = alloc((size_t)NN * HID * 4);
  float* abuf   = alloc((size_t)NN * HID * 4);
  float* pooled = alloc((size_t)(NG * HID + NG) * 4);
  float* cnt    = pooled + NG * HID;
  (void)ws_size; (void)in_sizes; (void)n_in; (void)out_size;

  const int nbN   = (NN + 255) / 256;
  const int nbE   = (NE + 255) / 256;
  const int nbN32 = (NN * 32 + 255) / 256;
  const int nbE32 = (NE * 32 + 255) / 256;

  k_init_deg<<<nbN, 256, 0, stream>>>(deg);
  k_count_deg<<<nbE, 256, 0, stream>>>(row, deg);
  k_dinv<<<nbN, 256, 0, stream>>>(deg);
  k_gather<<<nbN32, 256, 0, stream>>>(H, emb, xbuf);

  for (int layer = 0; layer < 2; ++layer) {
    const float* W = layer ? W2 : W1;
    const float* bb = layer ? b2 : b1;
    k_gemm<<<dim3((NN + 63) / 64, 2), 256, 0, stream>>>(xbuf, W, bb, hbuf);
    k_scale<<<nbN32, 256, 0, stream>>>(hbuf, abuf, deg);
    k_edges<<<nbE32, 256, 0, stream>>>(row, col, hbuf, abuf);
    k_relu_scale<<<nbN32, 256, 0, stream>>>(abuf, deg, xbuf);
  }

  hipMemsetAsync(pooled, 0, (size_t)(NG * HID + NG) * 4, stream);
  k_pool<<<nbN32, 256, 0, stream>>>(batch, xbuf, pooled, cnt);
  k_out<<<NG, NOUT_, 0, stream>>>(pooled, cnt, Wout, bout, (float*)d_out);
}

// Round 2
// 568.296 us; speedup vs baseline: 4.1924x; 4.1924x over previous
//
#include <hip/hip_runtime.h>

#define NN   50000
#define NE   600000
#define HID  128
#define NOUT_ 64
#define NG   256

// ---- CSR build -------------------------------------------------------------

static __global__ void k_count(const int* __restrict__ row, int* __restrict__ cnts) {
  int e = blockIdx.x * 256 + threadIdx.x;
  if (e < NE) atomicAdd(&cnts[row[e]], 1);
}

// exclusive scan of cnts[0..NN-1] -> base[0..NN], single block of 1024 threads
static __global__ __launch_bounds__(1024) void k_scan(const int* __restrict__ cnts,
                                                      int* __restrict__ base) {
  __shared__ int part[1024];
  const int tid = threadIdx.x;
  const int CH = (NN + 1023) / 1024;  // 49
  const int start = tid * CH;
  int s = 0;
  for (int i = 0; i < CH; ++i) {
    int idx = start + i;
    if (idx < NN) s += cnts[idx];
  }
  part[tid] = s;
  __syncthreads();
  for (int ofs = 1; ofs < 1024; ofs <<= 1) {
    int v = 0;
    if (tid >= ofs) v = part[tid - ofs];
    __syncthreads();
    if (tid >= ofs) part[tid] += v;
    __syncthreads();
  }
  int run = (tid == 0) ? 0 : part[tid - 1];
  for (int i = 0; i < CH; ++i) {
    int idx = start + i;
    if (idx < NN) { base[idx] = run; run += cnts[idx]; }
  }
  if (tid == 1023) base[NN] = run;  // = NE
}

static __global__ void k_scatter(const int* __restrict__ row, const int* __restrict__ col,
                                 const int* __restrict__ base, int* __restrict__ cursor,
                                 int* __restrict__ colIdx) {
  int e = blockIdx.x * 256 + threadIdx.x;
  if (e >= NE) return;
  int r = row[e];
  int pos = base[r] + atomicAdd(&cursor[r], 1);
  colIdx[pos] = col[e];
}

static __global__ void k_dinv(const int* __restrict__ cnts, float* __restrict__ dinv) {
  int i = blockIdx.x * 256 + threadIdx.x;
  if (i < NN) dinv[i] = rsqrtf((float)(cnts[i] + 1));  // +1 self-loop
}

// ---- feature pipeline ------------------------------------------------------

static __global__ void k_gather(const int* __restrict__ H, const float* __restrict__ emb,
                                float* __restrict__ x) {
  int t = blockIdx.x * 256 + threadIdx.x;
  int i = t >> 5;
  if (i >= NN) return;
  int j = (t & 31) << 2;
  *reinterpret_cast<float4*>(&x[i * HID + j]) =
      *reinterpret_cast<const float4*>(&emb[H[i] * HID + j]);
}

// g = (x @ W^T + b) * dinv[row]   (x: NN x 128, W: 128 x 128 row-major)
static __global__ __launch_bounds__(256) void k_gemm(
    const float* __restrict__ x, const float* __restrict__ W,
    const float* __restrict__ b, const float* __restrict__ dinv,
    float* __restrict__ g) {
  __shared__ float xsT[64][68];  // [k][row]
  __shared__ float wsT[64][68];  // [k][col]
  const int row0 = blockIdx.x * 64;
  const int col0 = blockIdx.y * 64;
  const int tid = threadIdx.x;
  const int tx = tid & 15, ty = tid >> 4;
  const int c0 = tx * 4, r0 = ty * 4;
  float acc[4][4] = {};
  for (int half = 0; half < 2; ++half) {
    const int kbase = half * 64;
    for (int it = 0; it < 4; ++it) {
      int idx = tid + it * 256;
      int r = idx >> 4;
      int k4 = (idx & 15) << 2;
      int gr = row0 + r;
      float4 xv = (gr < NN)
          ? *reinterpret_cast<const float4*>(&x[gr * HID + kbase + k4])
          : make_float4(0.f, 0.f, 0.f, 0.f);
      xsT[k4 + 0][r] = xv.x; xsT[k4 + 1][r] = xv.y;
      xsT[k4 + 2][r] = xv.z; xsT[k4 + 3][r] = xv.w;
      float4 wv = *reinterpret_cast<const float4*>(&W[(col0 + r) * HID + kbase + k4]);
      wsT[k4 + 0][r] = wv.x; wsT[k4 + 1][r] = wv.y;
      wsT[k4 + 2][r] = wv.z; wsT[k4 + 3][r] = wv.w;
    }
    __syncthreads();
#pragma unroll 8
    for (int k = 0; k < 64; ++k) {
      float xv[4], wv[4];
      *reinterpret_cast<float4*>(xv) = *reinterpret_cast<const float4*>(&xsT[k][r0]);
      *reinterpret_cast<float4*>(wv) = *reinterpret_cast<const float4*>(&wsT[k][c0]);
#pragma unroll
      for (int r = 0; r < 4; ++r)
#pragma unroll
        for (int c = 0; c < 4; ++c)
          acc[r][c] += xv[r] * wv[c];
    }
    __syncthreads();
  }
#pragma unroll
  for (int r = 0; r < 4; ++r) {
    int gr = row0 + r0 + r;
    if (gr < NN) {
      float d = dinv[gr];
      float4 o;
      o.x = (acc[r][0] + b[col0 + c0 + 0]) * d;
      o.y = (acc[r][1] + b[col0 + c0 + 1]) * d;
      o.z = (acc[r][2] + b[col0 + c0 + 2]) * d;
      o.w = (acc[r][3] + b[col0 + c0 + 3]) * d;
      *reinterpret_cast<float4*>(&g[gr * HID + col0 + c0]) = o;
    }
  }
}

// x[node] = relu( dinv[node] * ( g[node] + sum_{c in adj(node)} g[c] ) )
static __global__ void k_csr(const int* __restrict__ base, const int* __restrict__ colIdx,
                             const float* __restrict__ g, const float* __restrict__ dinv,
                             float* __restrict__ x) {
  int t = blockIdx.x * 256 + threadIdx.x;
  int node = t >> 5;
  if (node >= NN) return;
  int j = (t & 31) << 2;
  float4 acc = *reinterpret_cast<const float4*>(&g[node * HID + j]);  // self-loop
  int s = base[node], e = base[node + 1];
  for (int i = s; i < e; ++i) {
    int c = colIdx[i];
    float4 v = *reinterpret_cast<const float4*>(&g[c * HID + j]);
    acc.x += v.x; acc.y += v.y; acc.z += v.z; acc.w += v.w;
  }
  float d = dinv[node];
  acc.x = fmaxf(acc.x * d, 0.f);
  acc.y = fmaxf(acc.y * d, 0.f);
  acc.z = fmaxf(acc.z * d, 0.f);
  acc.w = fmaxf(acc.w * d, 0.f);
  *reinterpret_cast<float4*>(&x[node * HID + j]) = acc;
}

// ---- pooling + head --------------------------------------------------------

static __global__ void k_pool(const int* __restrict__ batch, const float* __restrict__ x,
                              float* __restrict__ pooled, float* __restrict__ cnt) {
  int t = blockIdx.x * 256 + threadIdx.x;
  int i = t >> 5;
  if (i >= NN) return;
  int j = (t & 31) << 2;
  int g = batch[i];
  float4 v = *reinterpret_cast<const float4*>(&x[i * HID + j]);
  float* dst = &pooled[g * HID + j];
  atomicAdd(dst + 0, v.x);
  atomicAdd(dst + 1, v.y);
  atomicAdd(dst + 2, v.z);
  atomicAdd(dst + 3, v.w);
  if (j == 0) atomicAdd(&cnt[g], 1.0f);
}

static __global__ void k_out(const float* __restrict__ pooled, const float* __restrict__ cnt,
                             const float* __restrict__ Wout, const float* __restrict__ bout,
                             float* __restrict__ out) {
  int g = blockIdx.x;
  int o = threadIdx.x;
  float inv = 1.0f / fmaxf(cnt[g], 1.0f);
  float acc = 0.f;
  for (int k = 0; k < HID; k += 4) {
    float4 p = *reinterpret_cast<const float4*>(&pooled[g * HID + k]);
    float4 w = *reinterpret_cast<const float4*>(&Wout[o * HID + k]);
    acc += p.x * w.x + p.y * w.y + p.z * w.z + p.w * w.w;
  }
  out[g * NOUT_ + o] = acc * inv + bout[o];
}

extern "C" void kernel_launch(void* const* d_in, const int* in_sizes, int n_in,
                              void* d_out, int out_size, void* d_ws, size_t ws_size,
                              hipStream_t stream) {
  const int* H     = (const int*)d_in[0];
  const int* ei    = (const int*)d_in[1];
  const int* row   = ei;
  const int* col   = ei + NE;
  const int* batch = (const int*)d_in[2];
  const float* emb  = (const float*)d_in[3];
  const float* W1   = (const float*)d_in[4];
  const float* b1   = (const float*)d_in[5];
  const float* W2   = (const float*)d_in[6];
  const float* b2   = (const float*)d_in[7];
  const float* Wout = (const float*)d_in[8];
  const float* bout = (const float*)d_in[9];

  char* ws = (char*)d_ws;
  size_t off = 0;
  auto alloc = [&](size_t bytes) -> void* {
    void* p = (void*)(ws + off);
    off += (bytes + 255) & ~(size_t)255;
    return p;
  };
  int*   cnts   = (int*)alloc((size_t)NN * 4);
  int*   cursor = (int*)alloc((size_t)NN * 4);
  int*   base   = (int*)alloc((size_t)(NN + 1) * 4);
  int*   colIdx = (int*)alloc((size_t)NE * 4);
  float* dinv   = (float*)alloc((size_t)NN * 4);
  float* xbuf   = (float*)alloc((size_t)NN * HID * 4);
  float* gbuf   = (float*)alloc((size_t)NN * HID * 4);
  float* pooled = (float*)alloc((size_t)(NG * HID + NG) * 4);
  float* cnt    = pooled + NG * HID;
  (void)ws_size; (void)in_sizes; (void)n_in; (void)out_size;

  const int nbN   = (NN + 255) / 256;
  const int nbE   = (NE + 255) / 256;
  const int nbN32 = (NN * 32 + 255) / 256;

  // CSR build + dinv
  hipMemsetAsync(cnts, 0, (size_t)NN * 4, stream);
  hipMemsetAsync(cursor, 0, (size_t)NN * 4, stream);
  k_count<<<nbE, 256, 0, stream>>>(row, cnts);
  k_scan<<<1, 1024, 0, stream>>>(cnts, base);
  k_scatter<<<nbE, 256, 0, stream>>>(row, col, base, cursor, colIdx);
  k_dinv<<<nbN, 256, 0, stream>>>(cnts, dinv);

  k_gather<<<nbN32, 256, 0, stream>>>(H, emb, xbuf);

  for (int layer = 0; layer < 2; ++layer) {
    const float* W  = layer ? W2 : W1;
    const float* bb = layer ? b2 : b1;
    k_gemm<<<dim3((NN + 63) / 64, 2), 256, 0, stream>>>(xbuf, W, bb, dinv, gbuf);
    k_csr<<<nbN32, 256, 0, stream>>>(base, colIdx, gbuf, dinv, xbuf);
  }

  hipMemsetAsync(pooled, 0, (size_t)(NG * HID + NG) * 4, stream);
  k_pool<<<nbN32, 256, 0, stream>>>(batch, xbuf, pooled, cnt);
  k_out<<<NG, NOUT_, 0, stream>>>(pooled, cnt, Wout, bout, (float*)d_out);
}

// Round 3
// 380.097 us; speedup vs baseline: 6.2683x; 1.4951x over previous
//
#include <hip/hip_runtime.h>

#define NN   50000
#define NE   600000
#define HID  128
#define NOUT_ 64
#define NG   256

// ---- CSR build -------------------------------------------------------------

static __global__ void k_count(const int* __restrict__ row, int* __restrict__ cnts) {
  int e = blockIdx.x * 256 + threadIdx.x;
  if (e < NE) atomicAdd(&cnts[row[e]], 1);
}

// exclusive scan of cnts[0..NN-1] -> base[0..NN], single block of 1024 threads
static __global__ __launch_bounds__(1024) void k_scan(const int* __restrict__ cnts,
                                                      int* __restrict__ base) {
  __shared__ int part[1024];
  const int tid = threadIdx.x;
  const int CH = (NN + 1023) / 1024;  // 49
  const int start = tid * CH;
  int s = 0;
  for (int i = 0; i < CH; ++i) {
    int idx = start + i;
    if (idx < NN) s += cnts[idx];
  }
  part[tid] = s;
  __syncthreads();
  for (int ofs = 1; ofs < 1024; ofs <<= 1) {
    int v = 0;
    if (tid >= ofs) v = part[tid - ofs];
    __syncthreads();
    if (tid >= ofs) part[tid] += v;
    __syncthreads();
  }
  int run = (tid == 0) ? 0 : part[tid - 1];
  for (int i = 0; i < CH; ++i) {
    int idx = start + i;
    if (idx < NN) { base[idx] = run; run += cnts[idx]; }
  }
  if (tid == 1023) base[NN] = run;  // = NE
}

static __global__ void k_scatter(const int* __restrict__ row, const int* __restrict__ col,
                                 const int* __restrict__ base, int* __restrict__ cursor,
                                 int* __restrict__ colIdx) {
  int e = blockIdx.x * 256 + threadIdx.x;
  if (e >= NE) return;
  int r = row[e];
  int pos = base[r] + atomicAdd(&cursor[r], 1);
  colIdx[pos] = col[e];
}

static __global__ void k_dinv(const int* __restrict__ cnts, float* __restrict__ dinv) {
  int i = blockIdx.x * 256 + threadIdx.x;
  if (i < NN) dinv[i] = rsqrtf((float)(cnts[i] + 1));  // +1 self-loop
}

// ---- feature pipeline ------------------------------------------------------

static __global__ void k_gather(const int* __restrict__ H, const float* __restrict__ emb,
                                float* __restrict__ x) {
  int t = blockIdx.x * 256 + threadIdx.x;
  int i = t >> 5;
  if (i >= NN) return;
  int j = (t & 31) << 2;
  *reinterpret_cast<float4*>(&x[i * HID + j]) =
      *reinterpret_cast<const float4*>(&emb[H[i] * HID + j]);
}

// g = (x @ W^T + b) * dinv[row]   (x: NN x 128, W: 128 x 128 row-major)
static __global__ __launch_bounds__(256) void k_gemm(
    const float* __restrict__ x, const float* __restrict__ W,
    const float* __restrict__ b, const float* __restrict__ dinv,
    float* __restrict__ g) {
  __shared__ float xsT[64][68];  // [k][row]
  __shared__ float wsT[64][68];  // [k][col]
  const int row0 = blockIdx.x * 64;
  const int col0 = blockIdx.y * 64;
  const int tid = threadIdx.x;
  const int tx = tid & 15, ty = tid >> 4;
  const int c0 = tx * 4, r0 = ty * 4;
  float acc[4][4] = {};
  for (int half = 0; half < 2; ++half) {
    const int kbase = half * 64;
    for (int it = 0; it < 4; ++it) {
      int idx = tid + it * 256;
      int r = idx >> 4;
      int k4 = (idx & 15) << 2;
      int gr = row0 + r;
      float4 xv = (gr < NN)
          ? *reinterpret_cast<const float4*>(&x[gr * HID + kbase + k4])
          : make_float4(0.f, 0.f, 0.f, 0.f);
      xsT[k4 + 0][r] = xv.x; xsT[k4 + 1][r] = xv.y;
      xsT[k4 + 2][r] = xv.z; xsT[k4 + 3][r] = xv.w;
      float4 wv = *reinterpret_cast<const float4*>(&W[(col0 + r) * HID + kbase + k4]);
      wsT[k4 + 0][r] = wv.x; wsT[k4 + 1][r] = wv.y;
      wsT[k4 + 2][r] = wv.z; wsT[k4 + 3][r] = wv.w;
    }
    __syncthreads();
#pragma unroll 8
    for (int k = 0; k < 64; ++k) {
      float xv[4], wv[4];
      *reinterpret_cast<float4*>(xv) = *reinterpret_cast<const float4*>(&xsT[k][r0]);
      *reinterpret_cast<float4*>(wv) = *reinterpret_cast<const float4*>(&wsT[k][c0]);
#pragma unroll
      for (int r = 0; r < 4; ++r)
#pragma unroll
        for (int c = 0; c < 4; ++c)
          acc[r][c] += xv[r] * wv[c];
    }
    __syncthreads();
  }
#pragma unroll
  for (int r = 0; r < 4; ++r) {
    int gr = row0 + r0 + r;
    if (gr < NN) {
      float d = dinv[gr];
      float4 o;
      o.x = (acc[r][0] + b[col0 + c0 + 0]) * d;
      o.y = (acc[r][1] + b[col0 + c0 + 1]) * d;
      o.z = (acc[r][2] + b[col0 + c0 + 2]) * d;
      o.w = (acc[r][3] + b[col0 + c0 + 3]) * d;
      *reinterpret_cast<float4*>(&g[gr * HID + col0 + c0]) = o;
    }
  }
}

// x[node] = relu( dinv[node] * ( g[node] + sum_{c in adj(node)} g[c] ) )
static __global__ void k_csr(const int* __restrict__ base, const int* __restrict__ colIdx,
                             const float* __restrict__ g, const float* __restrict__ dinv,
                             float* __restrict__ x) {
  int t = blockIdx.x * 256 + threadIdx.x;
  int node = t >> 5;
  if (node >= NN) return;
  int j = (t & 31) << 2;
  float4 acc = *reinterpret_cast<const float4*>(&g[node * HID + j]);  // self-loop
  int s = base[node], e = base[node + 1];
  for (int i = s; i < e; ++i) {
    int c = colIdx[i];
    float4 v = *reinterpret_cast<const float4*>(&g[c * HID + j]);
    acc.x += v.x; acc.y += v.y; acc.z += v.z; acc.w += v.w;
  }
  float d = dinv[node];
  acc.x = fmaxf(acc.x * d, 0.f);
  acc.y = fmaxf(acc.y * d, 0.f);
  acc.z = fmaxf(acc.z * d, 0.f);
  acc.w = fmaxf(acc.w * d, 0.f);
  *reinterpret_cast<float4*>(&x[node * HID + j]) = acc;
}

// ---- fused mean-pool + head (batch is SORTED) ------------------------------

static __device__ __forceinline__ int lb(const int* __restrict__ b, int n, int v) {
  int lo = 0, hi = n;
  while (lo < hi) { int m = (lo + hi) >> 1; if (b[m] < v) lo = m + 1; else hi = m; }
  return lo;
}

// one block (256 thr) per graph: mean over node range, then out = pooled@Wout^T+bout
static __global__ __launch_bounds__(256) void k_pool_out(
    const int* __restrict__ batch, const float* __restrict__ x,
    const float* __restrict__ Wout, const float* __restrict__ bout,
    float* __restrict__ out) {
  const int g = blockIdx.x;
  const int tid = threadIdx.x;
  const int s = lb(batch, NN, g);
  const int e = lb(batch, NN, g + 1);
  const float inv = 1.0f / fmaxf((float)(e - s), 1.0f);

  const int d = tid & 127;     // dim
  const int half = tid >> 7;   // 0/1: rows s+half, s+half+2, ...
  float acc = 0.f;
  for (int i = s + half; i < e; i += 2) acc += x[i * HID + d];

  __shared__ float tmp[256];
  __shared__ float pooled[HID];
  tmp[tid] = acc;
  __syncthreads();
  if (tid < HID) pooled[tid] = (tmp[tid] + tmp[tid + HID]) * inv;
  __syncthreads();

  // 64 outputs, 4 threads each (consecutive lanes -> same wave)
  const int o = tid >> 2, q = tid & 3;
  const float* wrow = &Wout[o * HID + q * 32];
  const float* prow = &pooled[q * 32];
  float a = 0.f;
#pragma unroll
  for (int k = 0; k < 32; k += 4) {
    float4 p = *reinterpret_cast<const float4*>(&prow[k]);
    float4 w = *reinterpret_cast<const float4*>(&wrow[k]);
    a += p.x * w.x + p.y * w.y + p.z * w.z + p.w * w.w;
  }
  a += __shfl_xor(a, 1);
  a += __shfl_xor(a, 2);
  if (q == 0) out[g * NOUT_ + o] = a + bout[o];
}

extern "C" void kernel_launch(void* const* d_in, const int* in_sizes, int n_in,
                              void* d_out, int out_size, void* d_ws, size_t ws_size,
                              hipStream_t stream) {
  const int* H     = (const int*)d_in[0];
  const int* ei    = (const int*)d_in[1];
  const int* row   = ei;
  const int* col   = ei + NE;
  const int* batch = (const int*)d_in[2];
  const float* emb  = (const float*)d_in[3];
  const float* W1   = (const float*)d_in[4];
  const float* b1   = (const float*)d_in[5];
  const float* W2   = (const float*)d_in[6];
  const float* b2   = (const float*)d_in[7];
  const float* Wout = (const float*)d_in[8];
  const float* bout = (const float*)d_in[9];

  char* ws = (char*)d_ws;
  size_t off = 0;
  auto alloc = [&](size_t bytes) -> void* {
    void* p = (void*)(ws + off);
    off += (bytes + 255) & ~(size_t)255;
    return p;
  };
  int*   cnts   = (int*)alloc((size_t)NN * 4);
  int*   cursor = (int*)alloc((size_t)NN * 4);
  int*   base   = (int*)alloc((size_t)(NN + 1) * 4);
  int*   colIdx = (int*)alloc((size_t)NE * 4);
  float* dinv   = (float*)alloc((size_t)NN * 4);
  float* xbuf   = (float*)alloc((size_t)NN * HID * 4);
  float* gbuf   = (float*)alloc((size_t)NN * HID * 4);
  (void)ws_size; (void)in_sizes; (void)n_in; (void)out_size;

  const int nbN   = (NN + 255) / 256;
  const int nbE   = (NE + 255) / 256;
  const int nbN32 = (NN * 32 + 255) / 256;

  // CSR build + dinv
  hipMemsetAsync(cnts, 0, (size_t)NN * 4, stream);
  hipMemsetAsync(cursor, 0, (size_t)NN * 4, stream);
  k_count<<<nbE, 256, 0, stream>>>(row, cnts);
  k_scan<<<1, 1024, 0, stream>>>(cnts, base);
  k_scatter<<<nbE, 256, 0, stream>>>(row, col, base, cursor, colIdx);
  k_dinv<<<nbN, 256, 0, stream>>>(cnts, dinv);

  k_gather<<<nbN32, 256, 0, stream>>>(H, emb, xbuf);

  for (int layer = 0; layer < 2; ++layer) {
    const float* W  = layer ? W2 : W1;
    const float* bb = layer ? b2 : b1;
    k_gemm<<<dim3((NN + 63) / 64, 2), 256, 0, stream>>>(xbuf, W, bb, dinv, gbuf);
    k_csr<<<nbN32, 256, 0, stream>>>(base, colIdx, gbuf, dinv, xbuf);
  }

  k_pool_out<<<NG, 256, 0, stream>>>(batch, xbuf, Wout, bout, (float*)d_out);
}

// Round 4
// 287.568 us; speedup vs baseline: 8.2852x; 1.3218x over previous
//
#include <hip/hip_runtime.h>

#define NN   50000
#define NE   600000
#define HID  128
#define NOUT_ 64
#define NG   256

#define SCAN_CHUNK 1024
#define SCAN_NB ((NN + SCAN_CHUNK - 1) / SCAN_CHUNK)  // 49

// ---- CSR build -------------------------------------------------------------

static __global__ void k_count(const int* __restrict__ row, int* __restrict__ cnts) {
  int e = blockIdx.x * 256 + threadIdx.x;
  if (e < NE) atomicAdd(&cnts[row[e]], 1);
}

// phase 1: per-block sums (each block covers 1024 cnts, 4/thread)
static __global__ __launch_bounds__(256) void k_scan1(const int* __restrict__ cnts,
                                                      int* __restrict__ bsum) {
  __shared__ int red[4];
  const int b = blockIdx.x, tid = threadIdx.x;
  const int start = b * SCAN_CHUNK + tid * 4;
  int s = 0;
#pragma unroll
  for (int i = 0; i < 4; ++i) {
    int idx = start + i;
    if (idx < NN) s += cnts[idx];
  }
#pragma unroll
  for (int o = 1; o < 64; o <<= 1) s += __shfl_xor(s, o);
  if ((tid & 63) == 0) red[tid >> 6] = s;
  __syncthreads();
  if (tid == 0) bsum[b] = red[0] + red[1] + red[2] + red[3];
}

// phase 2: exclusive scan of bsum[SCAN_NB] -> boff, one wave
static __global__ void k_scan2(const int* __restrict__ bsum, int* __restrict__ boff) {
  const int tid = threadIdx.x;  // 64 threads
  int orig = (tid < SCAN_NB) ? bsum[tid] : 0;
  int v = orig;
#pragma unroll
  for (int o = 1; o < 64; o <<= 1) {
    int u = __shfl_up(v, o);
    if (tid >= o) v += u;
  }
  if (tid < SCAN_NB) boff[tid] = v - orig;
}

// phase 3: local exclusive scan + block offset -> base
static __global__ __launch_bounds__(256) void k_scan3(const int* __restrict__ cnts,
                                                      const int* __restrict__ boff,
                                                      int* __restrict__ base) {
  __shared__ int wsum[4];
  const int b = blockIdx.x, tid = threadIdx.x;
  const int start = b * SCAN_CHUNK + tid * 4;
  int c[4];
  int s = 0;
#pragma unroll
  for (int i = 0; i < 4; ++i) {
    int idx = start + i;
    c[i] = (idx < NN) ? cnts[idx] : 0;
    s += c[i];
  }
  const int orig = s;
  const int lane = tid & 63, w = tid >> 6;
#pragma unroll
  for (int o = 1; o < 64; o <<= 1) {
    int u = __shfl_up(s, o);
    if (lane >= o) s += u;
  }
  if (lane == 63) wsum[w] = s;
  __syncthreads();
  int ex = s - orig + boff[b];
  for (int i = 0; i < w; ++i) ex += wsum[i];
#pragma unroll
  for (int i = 0; i < 4; ++i) {
    int idx = start + i;
    if (idx < NN) { base[idx] = ex; ex += c[i]; }
  }
  if (b == 0 && tid == 0) base[NN] = NE;
}

static __global__ void k_scatter(const int* __restrict__ row, const int* __restrict__ col,
                                 const int* __restrict__ base, int* __restrict__ cursor,
                                 int* __restrict__ colIdx) {
  int e = blockIdx.x * 256 + threadIdx.x;
  if (e >= NE) return;
  int r = row[e];
  int pos = base[r] + atomicAdd(&cursor[r], 1);
  colIdx[pos] = col[e];
}

static __global__ void k_dinv(const int* __restrict__ cnts, float* __restrict__ dinv) {
  int i = blockIdx.x * 256 + threadIdx.x;
  if (i < NN) dinv[i] = rsqrtf((float)(cnts[i] + 1));  // +1 self-loop
}

// ---- feature pipeline ------------------------------------------------------

// g = (src @ W^T + b) * dinv[row]; src row i is x[i] or emb[H[i]] when H!=nullptr
static __global__ __launch_bounds__(256) void k_gemm(
    const float* __restrict__ x, const int* __restrict__ H,
    const float* __restrict__ emb, const float* __restrict__ W,
    const float* __restrict__ b, const float* __restrict__ dinv,
    float* __restrict__ g) {
  __shared__ float xsT[64][68];  // [k][row]
  __shared__ float wsT[64][68];  // [k][col]
  const int row0 = blockIdx.x * 64;
  const int col0 = blockIdx.y * 64;
  const int tid = threadIdx.x;
  const int tx = tid & 15, ty = tid >> 4;
  const int c0 = tx * 4, r0 = ty * 4;
  float acc[4][4] = {};
  for (int half = 0; half < 2; ++half) {
    const int kbase = half * 64;
    for (int it = 0; it < 4; ++it) {
      int idx = tid + it * 256;
      int r = idx >> 4;
      int k4 = (idx & 15) << 2;
      int gr = row0 + r;
      float4 xv;
      if (gr < NN) {
        const float* src = H ? &emb[(size_t)H[gr] * HID] : &x[(size_t)gr * HID];
        xv = *reinterpret_cast<const float4*>(&src[kbase + k4]);
      } else {
        xv = make_float4(0.f, 0.f, 0.f, 0.f);
      }
      xsT[k4 + 0][r] = xv.x; xsT[k4 + 1][r] = xv.y;
      xsT[k4 + 2][r] = xv.z; xsT[k4 + 3][r] = xv.w;
      float4 wv = *reinterpret_cast<const float4*>(&W[(col0 + r) * HID + kbase + k4]);
      wsT[k4 + 0][r] = wv.x; wsT[k4 + 1][r] = wv.y;
      wsT[k4 + 2][r] = wv.z; wsT[k4 + 3][r] = wv.w;
    }
    __syncthreads();
#pragma unroll 8
    for (int k = 0; k < 64; ++k) {
      float xv[4], wv[4];
      *reinterpret_cast<float4*>(xv) = *reinterpret_cast<const float4*>(&xsT[k][r0]);
      *reinterpret_cast<float4*>(wv) = *reinterpret_cast<const float4*>(&wsT[k][c0]);
#pragma unroll
      for (int r = 0; r < 4; ++r)
#pragma unroll
        for (int c = 0; c < 4; ++c)
          acc[r][c] += xv[r] * wv[c];
    }
    __syncthreads();
  }
#pragma unroll
  for (int r = 0; r < 4; ++r) {
    int gr = row0 + r0 + r;
    if (gr < NN) {
      float d = dinv[gr];
      float4 o;
      o.x = (acc[r][0] + b[col0 + c0 + 0]) * d;
      o.y = (acc[r][1] + b[col0 + c0 + 1]) * d;
      o.z = (acc[r][2] + b[col0 + c0 + 2]) * d;
      o.w = (acc[r][3] + b[col0 + c0 + 3]) * d;
      *reinterpret_cast<float4*>(&g[gr * HID + col0 + c0]) = o;
    }
  }
}

// x[node] = relu( dinv[node] * ( g[node] + sum_{c in adj(node)} g[c] ) )
static __global__ void k_csr(const int* __restrict__ base, const int* __restrict__ colIdx,
                             const float* __restrict__ g, const float* __restrict__ dinv,
                             float* __restrict__ x) {
  int t = blockIdx.x * 256 + threadIdx.x;
  int node = t >> 5;
  if (node >= NN) return;
  int j = (t & 31) << 2;
  float4 acc = *reinterpret_cast<const float4*>(&g[node * HID + j]);  // self-loop
  int s = base[node], e = base[node + 1];
  for (int i = s; i < e; ++i) {
    int c = colIdx[i];
    float4 v = *reinterpret_cast<const float4*>(&g[c * HID + j]);
    acc.x += v.x; acc.y += v.y; acc.z += v.z; acc.w += v.w;
  }
  float d = dinv[node];
  acc.x = fmaxf(acc.x * d, 0.f);
  acc.y = fmaxf(acc.y * d, 0.f);
  acc.z = fmaxf(acc.z * d, 0.f);
  acc.w = fmaxf(acc.w * d, 0.f);
  *reinterpret_cast<float4*>(&x[node * HID + j]) = acc;
}

// ---- fused mean-pool + head (batch is SORTED) ------------------------------

static __device__ __forceinline__ int lb(const int* __restrict__ b, int n, int v) {
  int lo = 0, hi = n;
  while (lo < hi) { int m = (lo + hi) >> 1; if (b[m] < v) lo = m + 1; else hi = m; }
  return lo;
}

static __global__ __launch_bounds__(256) void k_pool_out(
    const int* __restrict__ batch, const float* __restrict__ x,
    const float* __restrict__ Wout, const float* __restrict__ bout,
    float* __restrict__ out) {
  const int g = blockIdx.x;
  const int tid = threadIdx.x;
  const int s = lb(batch, NN, g);
  const int e = lb(batch, NN, g + 1);
  const float inv = 1.0f / fmaxf((float)(e - s), 1.0f);

  const int d = tid & 127;
  const int half = tid >> 7;
  float acc = 0.f;
  for (int i = s + half; i < e; i += 2) acc += x[i * HID + d];

  __shared__ float tmp[256];
  __shared__ float pooled[HID];
  tmp[tid] = acc;
  __syncthreads();
  if (tid < HID) pooled[tid] = (tmp[tid] + tmp[tid + HID]) * inv;
  __syncthreads();

  const int o = tid >> 2, q = tid & 3;
  const float* wrow = &Wout[o * HID + q * 32];
  const float* prow = &pooled[q * 32];
  float a = 0.f;
#pragma unroll
  for (int k = 0; k < 32; k += 4) {
    float4 p = *reinterpret_cast<const float4*>(&prow[k]);
    float4 w = *reinterpret_cast<const float4*>(&wrow[k]);
    a += p.x * w.x + p.y * w.y + p.z * w.z + p.w * w.w;
  }
  a += __shfl_xor(a, 1);
  a += __shfl_xor(a, 2);
  if (q == 0) out[g * NOUT_ + o] = a + bout[o];
}

extern "C" void kernel_launch(void* const* d_in, const int* in_sizes, int n_in,
                              void* d_out, int out_size, void* d_ws, size_t ws_size,
                              hipStream_t stream) {
  const int* H     = (const int*)d_in[0];
  const int* ei    = (const int*)d_in[1];
  const int* row   = ei;
  const int* col   = ei + NE;
  const int* batch = (const int*)d_in[2];
  const float* emb  = (const float*)d_in[3];
  const float* W1   = (const float*)d_in[4];
  const float* b1   = (const float*)d_in[5];
  const float* W2   = (const float*)d_in[6];
  const float* b2   = (const float*)d_in[7];
  const float* Wout = (const float*)d_in[8];
  const float* bout = (const float*)d_in[9];

  char* ws = (char*)d_ws;
  size_t off = 0;
  auto alloc = [&](size_t bytes) -> void* {
    void* p = (void*)(ws + off);
    off += (bytes + 255) & ~(size_t)255;
    return p;
  };
  int*   cnts   = (int*)alloc((size_t)NN * 4);
  int*   cursor = (int*)alloc((size_t)NN * 4);
  int*   base   = (int*)alloc((size_t)(NN + 1) * 4);
  int*   bsum   = (int*)alloc((size_t)SCAN_NB * 4);
  int*   boff   = (int*)alloc((size_t)SCAN_NB * 4);
  int*   colIdx = (int*)alloc((size_t)NE * 4);
  float* dinv   = (float*)alloc((size_t)NN * 4);
  float* xbuf   = (float*)alloc((size_t)NN * HID * 4);
  float* gbuf   = (float*)alloc((size_t)NN * HID * 4);
  (void)ws_size; (void)in_sizes; (void)n_in; (void)out_size;

  const int nbN   = (NN + 255) / 256;
  const int nbE   = (NE + 255) / 256;
  const int nbN32 = (NN * 32 + 255) / 256;

  // CSR build + dinv
  hipMemsetAsync(cnts, 0, (size_t)NN * 4, stream);
  hipMemsetAsync(cursor, 0, (size_t)NN * 4, stream);
  k_count<<<nbE, 256, 0, stream>>>(row, cnts);
  k_scan1<<<SCAN_NB, 256, 0, stream>>>(cnts, bsum);
  k_scan2<<<1, 64, 0, stream>>>(bsum, boff);
  k_scan3<<<SCAN_NB, 256, 0, stream>>>(cnts, boff, base);
  k_scatter<<<nbE, 256, 0, stream>>>(row, col, base, cursor, colIdx);
  k_dinv<<<nbN, 256, 0, stream>>>(cnts, dinv);

  for (int layer = 0; layer < 2; ++layer) {
    const float* W  = layer ? W2 : W1;
    const float* bb = layer ? b2 : b1;
    k_gemm<<<dim3((NN + 63) / 64, 2), 256, 0, stream>>>(
        xbuf, layer ? nullptr : H, emb, W, bb, dinv, gbuf);
    k_csr<<<nbN32, 256, 0, stream>>>(base, colIdx, gbuf, dinv, xbuf);
  }

  k_pool_out<<<NG, 256, 0, stream>>>(batch, xbuf, Wout, bout, (float*)d_out);
}

// Round 5
// 239.209 us; speedup vs baseline: 9.9601x; 1.2022x over previous
//
#include <hip/hip_runtime.h>

#define NN   50000
#define NE   600000
#define HID  128
#define NOUT_ 64
#define NG   256

#define SCAN_CHUNK 1024
#define SCAN_NB ((NN + SCAN_CHUNK - 1) / SCAN_CHUNK)  // 49

typedef unsigned int u32;
typedef unsigned short u16;

// bf16 helpers (bit ops; accumulate in f32, store RNE bf16)
static __device__ __forceinline__ float bflo(u32 u) { return __uint_as_float(u << 16); }
static __device__ __forceinline__ float bfhi(u32 u) { return __uint_as_float(u & 0xffff0000u); }
static __device__ __forceinline__ u32 pack2bf(float lo, float hi) {
  u32 ul = __float_as_uint(lo), uh = __float_as_uint(hi);
  ul = (ul + 0x7fffu + ((ul >> 16) & 1u)) >> 16;
  uh = (uh + 0x7fffu + ((uh >> 16) & 1u)) >> 16;
  return ul | (uh << 16);
}

// ---- CSR build -------------------------------------------------------------

static __global__ void k_count(const int* __restrict__ row, int* __restrict__ cnts) {
  int e = blockIdx.x * 256 + threadIdx.x;
  if (e < NE) atomicAdd(&cnts[row[e]], 1);
}

static __global__ __launch_bounds__(256) void k_scan1(const int* __restrict__ cnts,
                                                      int* __restrict__ bsum) {
  __shared__ int red[4];
  const int b = blockIdx.x, tid = threadIdx.x;
  const int start = b * SCAN_CHUNK + tid * 4;
  int s = 0;
#pragma unroll
  for (int i = 0; i < 4; ++i) {
    int idx = start + i;
    if (idx < NN) s += cnts[idx];
  }
#pragma unroll
  for (int o = 1; o < 64; o <<= 1) s += __shfl_xor(s, o);
  if ((tid & 63) == 0) red[tid >> 6] = s;
  __syncthreads();
  if (tid == 0) bsum[b] = red[0] + red[1] + red[2] + red[3];
}

static __global__ void k_scan2(const int* __restrict__ bsum, int* __restrict__ boff) {
  const int tid = threadIdx.x;  // 64 threads
  int orig = (tid < SCAN_NB) ? bsum[tid] : 0;
  int v = orig;
#pragma unroll
  for (int o = 1; o < 64; o <<= 1) {
    int u = __shfl_up(v, o);
    if (tid >= o) v += u;
  }
  if (tid < SCAN_NB) boff[tid] = v - orig;
}

// local exclusive scan + block offset -> base; also emits dinv (fused)
static __global__ __launch_bounds__(256) void k_scan3(const int* __restrict__ cnts,
                                                      const int* __restrict__ boff,
                                                      int* __restrict__ base,
                                                      float* __restrict__ dinv) {
  __shared__ int wsum[4];
  const int b = blockIdx.x, tid = threadIdx.x;
  const int start = b * SCAN_CHUNK + tid * 4;
  int c[4];
  int s = 0;
#pragma unroll
  for (int i = 0; i < 4; ++i) {
    int idx = start + i;
    c[i] = (idx < NN) ? cnts[idx] : 0;
    s += c[i];
  }
  const int orig = s;
  const int lane = tid & 63, w = tid >> 6;
#pragma unroll
  for (int o = 1; o < 64; o <<= 1) {
    int u = __shfl_up(s, o);
    if (lane >= o) s += u;
  }
  if (lane == 63) wsum[w] = s;
  __syncthreads();
  int ex = s - orig + boff[b];
  for (int i = 0; i < w; ++i) ex += wsum[i];
#pragma unroll
  for (int i = 0; i < 4; ++i) {
    int idx = start + i;
    if (idx < NN) {
      base[idx] = ex;
      ex += c[i];
      dinv[idx] = rsqrtf((float)(c[i] + 1));  // +1 self-loop
    }
  }
  if (b == 0 && tid == 0) base[NN] = NE;
}

static __global__ void k_scatter(const int* __restrict__ row, const int* __restrict__ col,
                                 const int* __restrict__ base, int* __restrict__ cursor,
                                 int* __restrict__ colIdx) {
  int e = blockIdx.x * 256 + threadIdx.x;
  if (e >= NE) return;
  int r = row[e];
  int pos = base[r] + atomicAdd(&cursor[r], 1);
  colIdx[pos] = col[e];
}

// ---- feature pipeline ------------------------------------------------------

// g(bf16) = (src @ W^T + b) * dinv[row]; src = emb[H[i]] (f32) if FIRST else x[i] (bf16)
template <bool FIRST>
static __global__ __launch_bounds__(256) void k_gemm(
    const u16* __restrict__ x, const int* __restrict__ H,
    const float* __restrict__ emb, const float* __restrict__ W,
    const float* __restrict__ b, const float* __restrict__ dinv,
    u16* __restrict__ g) {
  __shared__ float xsT[64][68];  // [k][row]
  __shared__ float wsT[64][68];  // [k][col]
  const int row0 = blockIdx.x * 64;
  const int col0 = blockIdx.y * 64;
  const int tid = threadIdx.x;
  const int tx = tid & 15, ty = tid >> 4;
  const int c0 = tx * 4, r0 = ty * 4;
  float acc[4][4] = {};
  for (int half = 0; half < 2; ++half) {
    const int kbase = half * 64;
    for (int it = 0; it < 4; ++it) {
      int idx = tid + it * 256;
      int r = idx >> 4;
      int k4 = (idx & 15) << 2;
      int gr = row0 + r;
      float f0, f1, f2, f3;
      if (gr < NN) {
        if (FIRST) {
          float4 xv = *reinterpret_cast<const float4*>(
              &emb[(size_t)H[gr] * HID + kbase + k4]);
          f0 = xv.x; f1 = xv.y; f2 = xv.z; f3 = xv.w;
        } else {
          uint2 xv = *reinterpret_cast<const uint2*>(
              (const u32*)x + (size_t)gr * (HID / 2) + ((kbase + k4) >> 1));
          f0 = bflo(xv.x); f1 = bfhi(xv.x); f2 = bflo(xv.y); f3 = bfhi(xv.y);
        }
      } else {
        f0 = f1 = f2 = f3 = 0.f;
      }
      xsT[k4 + 0][r] = f0; xsT[k4 + 1][r] = f1;
      xsT[k4 + 2][r] = f2; xsT[k4 + 3][r] = f3;
      float4 wv = *reinterpret_cast<const float4*>(&W[(col0 + r) * HID + kbase + k4]);
      wsT[k4 + 0][r] = wv.x; wsT[k4 + 1][r] = wv.y;
      wsT[k4 + 2][r] = wv.z; wsT[k4 + 3][r] = wv.w;
    }
    __syncthreads();
#pragma unroll 8
    for (int k = 0; k < 64; ++k) {
      float xv[4], wv[4];
      *reinterpret_cast<float4*>(xv) = *reinterpret_cast<const float4*>(&xsT[k][r0]);
      *reinterpret_cast<float4*>(wv) = *reinterpret_cast<const float4*>(&wsT[k][c0]);
#pragma unroll
      for (int r = 0; r < 4; ++r)
#pragma unroll
        for (int c = 0; c < 4; ++c)
          acc[r][c] += xv[r] * wv[c];
    }
    __syncthreads();
  }
#pragma unroll
  for (int r = 0; r < 4; ++r) {
    int gr = row0 + r0 + r;
    if (gr < NN) {
      float d = dinv[gr];
      float o0 = (acc[r][0] + b[col0 + c0 + 0]) * d;
      float o1 = (acc[r][1] + b[col0 + c0 + 1]) * d;
      float o2 = (acc[r][2] + b[col0 + c0 + 2]) * d;
      float o3 = (acc[r][3] + b[col0 + c0 + 3]) * d;
      *reinterpret_cast<uint2*>((u32*)g + (size_t)gr * (HID / 2) + ((col0 + c0) >> 1)) =
          make_uint2(pack2bf(o0, o1), pack2bf(o2, o3));
    }
  }
}

// x[node](bf16) = relu( dinv[node] * ( g[node] + sum_{c in adj(node)} g[c] ) )
// 32 lanes per node, 4 dims per lane; edge loop unrolled x4 for MLP
static __global__ void k_csr(const int* __restrict__ base, const int* __restrict__ colIdx,
                             const u16* __restrict__ g, const float* __restrict__ dinv,
                             u16* __restrict__ x) {
  int t = blockIdx.x * 256 + threadIdx.x;
  int node = t >> 5;
  if (node >= NN) return;
  const int lane2 = (t & 31) * 2;  // u32 index within row (HID/2 = 64 u32)
  const u32* gw = (const u32*)g;

  uint2 v = *reinterpret_cast<const uint2*>(gw + (size_t)node * 64 + lane2);  // self
  float a0 = bflo(v.x), a1 = bfhi(v.x), a2 = bflo(v.y), a3 = bfhi(v.y);

  const int s = base[node], e = base[node + 1];
  int i = s;
  for (; i + 4 <= e; i += 4) {
    int c0 = colIdx[i], c1 = colIdx[i + 1], c2 = colIdx[i + 2], c3 = colIdx[i + 3];
    uint2 w0 = *reinterpret_cast<const uint2*>(gw + (size_t)c0 * 64 + lane2);
    uint2 w1 = *reinterpret_cast<const uint2*>(gw + (size_t)c1 * 64 + lane2);
    uint2 w2 = *reinterpret_cast<const uint2*>(gw + (size_t)c2 * 64 + lane2);
    uint2 w3 = *reinterpret_cast<const uint2*>(gw + (size_t)c3 * 64 + lane2);
    a0 += bflo(w0.x) + bflo(w1.x) + bflo(w2.x) + bflo(w3.x);
    a1 += bfhi(w0.x) + bfhi(w1.x) + bfhi(w2.x) + bfhi(w3.x);
    a2 += bflo(w0.y) + bflo(w1.y) + bflo(w2.y) + bflo(w3.y);
    a3 += bfhi(w0.y) + bfhi(w1.y) + bfhi(w2.y) + bfhi(w3.y);
  }
  for (; i < e; ++i) {
    uint2 w = *reinterpret_cast<const uint2*>(gw + (size_t)colIdx[i] * 64 + lane2);
    a0 += bflo(w.x); a1 += bfhi(w.x); a2 += bflo(w.y); a3 += bfhi(w.y);
  }
  float d = dinv[node];
  a0 = fmaxf(a0 * d, 0.f);
  a1 = fmaxf(a1 * d, 0.f);
  a2 = fmaxf(a2 * d, 0.f);
  a3 = fmaxf(a3 * d, 0.f);
  *reinterpret_cast<uint2*>((u32*)x + (size_t)node * 64 + lane2) =
      make_uint2(pack2bf(a0, a1), pack2bf(a2, a3));
}

// ---- fused mean-pool + head (batch is SORTED) ------------------------------

static __device__ __forceinline__ int lb(const int* __restrict__ b, int n, int v) {
  int lo = 0, hi = n;
  while (lo < hi) { int m = (lo + hi) >> 1; if (b[m] < v) lo = m + 1; else hi = m; }
  return lo;
}

static __global__ __launch_bounds__(256) void k_pool_out(
    const int* __restrict__ batch, const u16* __restrict__ x,
    const float* __restrict__ Wout, const float* __restrict__ bout,
    float* __restrict__ out) {
  const int g = blockIdx.x;
  const int tid = threadIdx.x;
  const int s = lb(batch, NN, g);
  const int e = lb(batch, NN, g + 1);
  const float inv = 1.0f / fmaxf((float)(e - s), 1.0f);

  const int d = tid & 127;
  const int half = tid >> 7;
  float acc = 0.f;
  for (int i = s + half; i < e; i += 2)
    acc += __uint_as_float(((u32)x[(size_t)i * HID + d]) << 16);

  __shared__ float tmp[256];
  __shared__ float pooled[HID];
  tmp[tid] = acc;
  __syncthreads();
  if (tid < HID) pooled[tid] = (tmp[tid] + tmp[tid + HID]) * inv;
  __syncthreads();

  const int o = tid >> 2, q = tid & 3;
  const float* wrow = &Wout[o * HID + q * 32];
  const float* prow = &pooled[q * 32];
  float a = 0.f;
#pragma unroll
  for (int k = 0; k < 32; k += 4) {
    float4 p = *reinterpret_cast<const float4*>(&prow[k]);
    float4 w = *reinterpret_cast<const float4*>(&wrow[k]);
    a += p.x * w.x + p.y * w.y + p.z * w.z + p.w * w.w;
  }
  a += __shfl_xor(a, 1);
  a += __shfl_xor(a, 2);
  if (q == 0) out[g * NOUT_ + o] = a + bout[o];
}

extern "C" void kernel_launch(void* const* d_in, const int* in_sizes, int n_in,
                              void* d_out, int out_size, void* d_ws, size_t ws_size,
                              hipStream_t stream) {
  const int* H     = (const int*)d_in[0];
  const int* ei    = (const int*)d_in[1];
  const int* row   = ei;
  const int* col   = ei + NE;
  const int* batch = (const int*)d_in[2];
  const float* emb  = (const float*)d_in[3];
  const float* W1   = (const float*)d_in[4];
  const float* b1   = (const float*)d_in[5];
  const float* W2   = (const float*)d_in[6];
  const float* b2   = (const float*)d_in[7];
  const float* Wout = (const float*)d_in[8];
  const float* bout = (const float*)d_in[9];

  char* ws = (char*)d_ws;
  size_t off = 0;
  auto alloc = [&](size_t bytes) -> void* {
    void* p = (void*)(ws + off);
    off += (bytes + 255) & ~(size_t)255;
    return p;
  };
  int*   cnts   = (int*)alloc((size_t)NN * 4);
  int*   cursor = (int*)alloc((size_t)NN * 4);
  int*   base   = (int*)alloc((size_t)(NN + 1) * 4);
  int*   bsum   = (int*)alloc((size_t)SCAN_NB * 4);
  int*   boff   = (int*)alloc((size_t)SCAN_NB * 4);
  int*   colIdx = (int*)alloc((size_t)NE * 4);
  float* dinv   = (float*)alloc((size_t)NN * 4);
  u16*   xbuf   = (u16*)alloc((size_t)NN * HID * 2);
  u16*   gbuf   = (u16*)alloc((size_t)NN * HID * 2);
  (void)ws_size; (void)in_sizes; (void)n_in; (void)out_size;

  const int nbE   = (NE + 255) / 256;
  const int nbN32 = (NN * 32 + 255) / 256;

  // CSR build + dinv
  hipMemsetAsync(cnts, 0, (size_t)NN * 4, stream);
  hipMemsetAsync(cursor, 0, (size_t)NN * 4, stream);
  k_count<<<nbE, 256, 0, stream>>>(row, cnts);
  k_scan1<<<SCAN_NB, 256, 0, stream>>>(cnts, bsum);
  k_scan2<<<1, 64, 0, stream>>>(bsum, boff);
  k_scan3<<<SCAN_NB, 256, 0, stream>>>(cnts, boff, base, dinv);
  k_scatter<<<nbE, 256, 0, stream>>>(row, col, base, cursor, colIdx);

  // layer 0 (reads emb[H]) then layer 1 (reads bf16 x)
  k_gemm<true><<<dim3((NN + 63) / 64, 2), 256, 0, stream>>>(
      nullptr, H, emb, W1, b1, dinv, gbuf);
  k_csr<<<nbN32, 256, 0, stream>>>(base, colIdx, gbuf, dinv, xbuf);
  k_gemm<false><<<dim3((NN + 63) / 64, 2), 256, 0, stream>>>(
      xbuf, nullptr, nullptr, W2, b2, dinv, gbuf);
  k_csr<<<nbN32, 256, 0, stream>>>(base, colIdx, gbuf, dinv, xbuf);

  k_pool_out<<<NG, 256, 0, stream>>>(batch, xbuf, Wout, bout, (float*)d_out);
}